// Round 1
// 178.304 us; speedup vs baseline: 1.0124x; 1.0124x over previous
//
#include <hip/hip_runtime.h>
#include <math.h>

// Problem constants (fixed by the reference file)
#define OUT_H 7
#define OUT_W 7
#define GS 2                      // SAMPLE_NUM
#define NBINS (OUT_H * OUT_W)     // 49
#define NSAMP (GS * GS)           // 4
#define NMETA (NBINS * NSAMP)     // 196 precomputed samples per roi
#define SPATIAL_SCALE 0.25f
#define B_ 2
#define C_ 256
#define H_ 200
#define W_ 200
#define R_ 1000
#define HW_ (H_ * W_)             // 40000
#define NBH 25                    // bins per pass (25 then 24)

typedef _Float16 half_t;
typedef __attribute__((ext_vector_type(4))) _Float16 half4;
typedef __attribute__((ext_vector_type(2))) _Float16 half2_t;

// ============================================================================
// Fast path: XCD-banded roi order + fp16 NHWC transform + coalesced gather
// ============================================================================

// ---- NCHW fp32 -> NHWC fp16 tiled transpose, with the roi->block permutation
// built by block (0,0,0) (absorbs the old single-block build_perm launch).
// Block id % 8 == (batch, cy-quartile) band; with id%8 XCD round-robin each
// XCD's co-resident rois share a spatial band (~5MB fp16 ~ one XCD L2).
// tile: 64 channels x 64 hw. grid (625, 4, 2), block 256.
__global__ __launch_bounds__(256)
void nchw_to_nhwc_h(const float* __restrict__ in, half_t* __restrict__ out,
                    const float* __restrict__ rois, int* __restrict__ perm) {
    __shared__ float tile[64][65];       // 16.6 KB, pad -> conflict-free

    // ---- perm build (block 0 only; ~3KB extra LDS, runs under the other
    // 4999 blocks' memory traffic) ----
    __shared__ int cnt[8];
    __shared__ int novf, take;
    __shared__ unsigned char claimed[R_];
    __shared__ short ovf[R_];
    if (blockIdx.x == 0 && blockIdx.y == 0 && blockIdx.z == 0) {
        const int t0 = threadIdx.x;
        if (t0 < 8) cnt[t0] = 0;
        if (t0 == 0) { novf = 0; take = 0; }
        for (int t = t0; t < R_; t += 256) claimed[t] = 0;
        __syncthreads();
        for (int t = t0; t < R_; t += 256) {
            const float* roi = rois + t * 6;
            int   b   = (int)roi[0];
            float cyf = roi[2] * SPATIAL_SCALE;          // ~25..175
            int q = (int)((cyf - 25.0f) * (4.0f / 150.0f));
            q = q < 0 ? 0 : (q > 3 ? 3 : q);
            int band = b * 4 + q;
            band = band < 0 ? 0 : (band > 7 ? 7 : band);
            int rank = atomicAdd(&cnt[band], 1);
            if (rank < R_ / 8) {
                int id = band + 8 * rank;
                perm[id] = t;
                claimed[id] = 1;
            } else {
                ovf[atomicAdd(&novf, 1)] = (short)t;
            }
        }
        __syncthreads();
        for (int t = t0; t < R_; t += 256) {
            if (!claimed[t]) perm[t] = (int)ovf[atomicAdd(&take, 1)];
        }
    }

    const int hw0 = blockIdx.x * 64;     // 625 tiles
    const int c0  = blockIdx.y * 64;     // 4 chunks
    const int b   = blockIdx.z;

    // read: lanes along hw (256B per wave-load), 64 c rows
    {
        const int tx = threadIdx.x & 63;      // hw
        const int ty = threadIdx.x >> 6;      // 0..3
        const float* ip = in + ((size_t)b * C_ + c0) * HW_ + hw0;
#pragma unroll
        for (int k = 0; k < 16; ++k)
            tile[ty + 4 * k][tx] = ip[(size_t)(ty + 4 * k) * HW_ + tx];
    }
    __syncthreads();
    // write: thread = (hw row, channel pair); half2 stores, 128B contiguous
    // per 32 lanes.
    {
        const int cp = threadIdx.x & 31;      // channel pair 0..31 (64 ch)
        const int hr = threadIdx.x >> 5;      // 0..7
        half_t* op = out + ((size_t)b * HW_ + hw0) * C_ + c0;
#pragma unroll
        for (int k = 0; k < 8; ++k) {
            const int hw = hr + 8 * k;
            half2_t h;
            h[0] = (half_t)tile[2 * cp + 0][hw];
            h[1] = (half_t)tile[2 * cp + 1][hw];
            ((half2_t*)(op + (size_t)hw * C_))[cp] = h;
        }
    }
}

// ---- one pass of the gather: bins B0..B0+NB-1, staged in 25.6KB LDS ----
// Sample metadata (offsets+weights) comes precomputed from LDS: the inner
// loop is 2 broadcast ds_read_b128 + 8 tap loads + 32 mix-FMAs per sample
// pair -- the wave-uniform coordinate math is NOT recomputed per lane here.
template<int B0, int NB>
__device__ __forceinline__ void gather_pass(
        const half4* __restrict__ fp,
        const int4* __restrict__ s_o, const float4* __restrict__ s_w,
        int wave, int lane, int tid,
        float (&obuf)[4][64][NBH], float* __restrict__ out_r) {

    for (int j = wave; j < NB; j += 8) {
        const int m = (B0 + j) * NSAMP;
        float ax = 0.0f, ay = 0.0f, az = 0.0f, aw = 0.0f;

#pragma unroll
        for (int sp = 0; sp < 2; ++sp) {
            const int4   oA = s_o[m + 2 * sp + 0];
            const int4   oB = s_o[m + 2 * sp + 1];
            const float4 wA = s_w[m + 2 * sp + 0];
            const float4 wB = s_w[m + 2 * sp + 1];

            // 8 tap loads in flight before the first use: 8B/lane, 512B/wave
            const half4 vA0 = fp[oA.x + lane];
            const half4 vA1 = fp[oA.y + lane];
            const half4 vA2 = fp[oA.z + lane];
            const half4 vA3 = fp[oA.w + lane];
            const half4 vB0 = fp[oB.x + lane];
            const half4 vB1 = fp[oB.y + lane];
            const half4 vB2 = fp[oB.z + lane];
            const half4 vB3 = fp[oB.w + lane];

            ax = fmaf((float)vA0[0], wA.x, ax);
            ay = fmaf((float)vA0[1], wA.x, ay);
            az = fmaf((float)vA0[2], wA.x, az);
            aw = fmaf((float)vA0[3], wA.x, aw);
            ax = fmaf((float)vA1[0], wA.y, ax);
            ay = fmaf((float)vA1[1], wA.y, ay);
            az = fmaf((float)vA1[2], wA.y, az);
            aw = fmaf((float)vA1[3], wA.y, aw);
            ax = fmaf((float)vA2[0], wA.z, ax);
            ay = fmaf((float)vA2[1], wA.z, ay);
            az = fmaf((float)vA2[2], wA.z, az);
            aw = fmaf((float)vA2[3], wA.z, aw);
            ax = fmaf((float)vA3[0], wA.w, ax);
            ay = fmaf((float)vA3[1], wA.w, ay);
            az = fmaf((float)vA3[2], wA.w, az);
            aw = fmaf((float)vA3[3], wA.w, aw);

            ax = fmaf((float)vB0[0], wB.x, ax);
            ay = fmaf((float)vB0[1], wB.x, ay);
            az = fmaf((float)vB0[2], wB.x, az);
            aw = fmaf((float)vB0[3], wB.x, aw);
            ax = fmaf((float)vB1[0], wB.y, ax);
            ay = fmaf((float)vB1[1], wB.y, ay);
            az = fmaf((float)vB1[2], wB.y, az);
            aw = fmaf((float)vB1[3], wB.y, aw);
            ax = fmaf((float)vB2[0], wB.z, ax);
            ay = fmaf((float)vB2[1], wB.z, ay);
            az = fmaf((float)vB2[2], wB.z, az);
            aw = fmaf((float)vB2[3], wB.z, aw);
            ax = fmaf((float)vB3[0], wB.w, ax);
            ay = fmaf((float)vB3[1], wB.w, ay);
            az = fmaf((float)vB3[2], wB.w, az);
            aw = fmaf((float)vB3[3], wB.w, aw);
        }

        // staging: addr = k*1600 + lane*25 + j; lane stride 25 (odd) -> free
        obuf[0][lane][j] = ax;   // c = 4*lane+0
        obuf[1][lane][j] = ay;   // c = 4*lane+1
        obuf[2][lane][j] = az;   // c = 4*lane+2
        obuf[3][lane][j] = aw;   // c = 4*lane+3
    }
    __syncthreads();

    // writeout: e = c*NB + j -> out_r[c*49 + B0 + j]. Regular stores so both
    // passes' partial rows merge in this XCD's L2 before writeback.
    const int E = C_ * NB;
#pragma unroll
    for (int i = 0; i < (E + 511) / 512; ++i) {
        const int e = tid + 512 * i;
        if (e < E) {
            const int c = e / NB;
            const int j = e - c * NB;
            out_r[(size_t)c * NBINS + B0 + j] = obuf[c & 3][c >> 2][j];
        }
    }
    __syncthreads();   // protect obuf reuse by next pass
}

// ---- gather from fp16 NHWC: one block (512 thr, 8 waves) per roi, 2 passes.
// Phase 0: 196 threads precompute all (bin,sample) offsets/weights into LDS
// (wave-uniform math computed ONCE per block instead of per lane per visit).
// 31.9KB LDS -> 4 blocks/CU (thread-capped); 1000 blocks -> single round.
__global__ __launch_bounds__(512, 8)
void gather_nhwc(const half_t* __restrict__ nhwc,
                 const float* __restrict__ rois,
                 const int* __restrict__ perm,
                 float* __restrict__ out) {
    __shared__ float obuf[4][64][NBH];   // 25600 B
    __shared__ int4   s_o[NMETA];        // 3136 B: 4 tap offsets (units of half4)
    __shared__ float4 s_w[NMETA];        // 3136 B: 4 tap weights (scale folded)

    const int r    = perm[blockIdx.x];
    const int tid  = threadIdx.x;
    const int wave = tid >> 6;   // 0..7
    const int lane = tid & 63;

    // ---- phase 0: per-(bin,sample) metadata (196 of 512 threads) ----
    if (tid < NMETA) {
        const float* roi = rois + r * 6;
        const int   b     = (int)roi[0];
        const float cx    = roi[1] * SPATIAL_SCALE - 0.5f;   // ALIGNED
        const float cy    = roi[2] * SPATIAL_SCALE - 0.5f;
        const float rw    = roi[3] * SPATIAL_SCALE;
        const float rh    = roi[4] * SPATIAL_SCALE;
        const float theta = roi[5];                           // CLOCKWISE == False
        const float bin_h = rh * (1.0f / OUT_H);
        const float bin_w = rw * (1.0f / OUT_W);
        float st, ct;
        __sincosf(theta, &st, &ct);

        const int bin = tid >> 2;          // 0..48
        const int s   = tid & 3;           // 0..3
        const int ph  = bin / OUT_W, pw = bin % OUT_W;
        const int iy  = s >> 1,      ix = s & 1;

        const float yy = -rh * 0.5f + ((float)ph + ((float)iy + 0.5f) * 0.5f) * bin_h;
        const float xx = -rw * 0.5f + ((float)pw + ((float)ix + 0.5f) * 0.5f) * bin_w;
        float x = yy * st + xx * ct + cx;
        float y = yy * ct - xx * st + cy;

        const bool valid = (y > -1.0f) && (y < (float)H_) &&
                           (x > -1.0f) && (x < (float)W_);
        y = fmaxf(y, 0.0f);
        x = fmaxf(x, 0.0f);
        int yl = (int)y, xl = (int)x;
        int yh; float ly;
        if (yl >= H_ - 1) { yl = H_ - 1; yh = H_ - 1; ly = 0.0f; }
        else              { yh = yl + 1; ly = y - (float)yl; }
        int xh; float lx;
        if (xl >= W_ - 1) { xl = W_ - 1; xh = W_ - 1; lx = 0.0f; }
        else              { xh = xl + 1; lx = x - (float)xl; }
        const float hy = 1.0f - ly, hx = 1.0f - lx;
        const float scale = valid ? (1.0f / NSAMP) : 0.0f;

        const int bplane = b * HW_;
        s_o[tid] = make_int4((bplane + yl * W_ + xl) * (C_ / 4),
                             (bplane + yl * W_ + xh) * (C_ / 4),
                             (bplane + yh * W_ + xl) * (C_ / 4),
                             (bplane + yh * W_ + xh) * (C_ / 4));
        s_w[tid] = make_float4(hy * hx * scale, hy * lx * scale,
                               ly * hx * scale, ly * lx * scale);
    }
    __syncthreads();

    const half4* __restrict__ fp = (const half4*)nhwc;
    float* out_r = out + (size_t)r * (C_ * NBINS);

    gather_pass< 0, 25>(fp, s_o, s_w, wave, lane, tid, obuf, out_r);
    gather_pass<25, 24>(fp, s_o, s_w, wave, lane, tid, obuf, out_r);
}

// ============================================================================
// Fallback path (round-0 structure, known-passing)
// ============================================================================

struct alignas(16) Samp {
    int o0, o1, o2, o3;
    float w0, w1, w2, w3;
};

__device__ __forceinline__ Samp compute_samp(const float* __restrict__ rois,
                                             int r, int ph, int pw, int s) {
    const float* roi = rois + r * 6;
    int   b     = (int)roi[0];
    float cx    = roi[1] * SPATIAL_SCALE - 0.5f;
    float cy    = roi[2] * SPATIAL_SCALE - 0.5f;
    float rw    = roi[3] * SPATIAL_SCALE;
    float rh    = roi[4] * SPATIAL_SCALE;
    float theta = roi[5];
    float bin_h = rh * (1.0f / OUT_H);
    float bin_w = rw * (1.0f / OUT_W);
    int iy = s / GS, ix = s % GS;
    float yy = -rh * 0.5f + ((float)ph + ((float)iy + 0.5f) * (1.0f / GS)) * bin_h;
    float xx = -rw * 0.5f + ((float)pw + ((float)ix + 0.5f) * (1.0f / GS)) * bin_w;
    float st = sinf(theta), ct = cosf(theta);
    float x = yy * st + xx * ct + cx;
    float y = yy * ct - xx * st + cy;
    bool valid = (y > -1.0f) && (y < (float)H_) && (x > -1.0f) && (x < (float)W_);
    y = fmaxf(y, 0.0f);
    x = fmaxf(x, 0.0f);
    int yl = (int)y;
    int xl = (int)x;
    int yh; float ly;
    if (yl >= H_ - 1) { yl = H_ - 1; yh = H_ - 1; ly = 0.0f; }
    else              { yh = yl + 1; ly = y - (float)yl; }
    int xh; float lx;
    if (xl >= W_ - 1) { xl = W_ - 1; xh = W_ - 1; lx = 0.0f; }
    else              { xh = xl + 1; lx = x - (float)xl; }
    float hy = 1.0f - ly, hx = 1.0f - lx;
    float scale = valid ? (1.0f / NSAMP) : 0.0f;
    Samp sp;
    int base = b * (C_ * H_ * W_);
    sp.o0 = base + yl * W_ + xl;
    sp.o1 = base + yl * W_ + xh;
    sp.o2 = base + yh * W_ + xl;
    sp.o3 = base + yh * W_ + xh;
    sp.w0 = hy * hx * scale;
    sp.w1 = hy * lx * scale;
    sp.w2 = ly * hx * scale;
    sp.w3 = ly * lx * scale;
    return sp;
}

__global__ __launch_bounds__(256)
void mono_kernel(const float* __restrict__ feat,
                 const float* __restrict__ rois,
                 float* __restrict__ out) {
    int tid = blockIdx.x * blockDim.x + threadIdx.x;
    if (tid >= R_ * C_ * NBINS) return;
    int bin = tid % NBINS;
    int rc  = tid / NBINS;
    int c   = rc % C_;
    int r   = rc / C_;
    int coff = c * (H_ * W_);
    float acc = 0.0f;
#pragma unroll
    for (int s = 0; s < NSAMP; ++s) {
        Samp t = compute_samp(rois, r, bin / OUT_W, bin % OUT_W, s);
        acc += t.w0 * feat[coff + t.o0];
        acc += t.w1 * feat[coff + t.o1];
        acc += t.w2 * feat[coff + t.o2];
        acc += t.w3 * feat[coff + t.o3];
    }
    out[tid] = acc;
}

// ============================================================================

extern "C" void kernel_launch(void* const* d_in, const int* in_sizes, int n_in,
                              void* d_out, int out_size, void* d_ws, size_t ws_size,
                              hipStream_t stream) {
    const float* feat = (const float*)d_in[0];
    const float* rois = (const float*)d_in[1];
    float* out = (float*)d_out;

    const size_t nhwc_bytes = (size_t)B_ * C_ * HW_ * sizeof(half_t);  // 41 MB
    const size_t perm_bytes = (size_t)R_ * sizeof(int);

    if (ws_size >= nhwc_bytes + perm_bytes) {
        half_t* nhwc = (half_t*)d_ws;
        int*    perm = (int*)((char*)d_ws + nhwc_bytes);
        dim3 tgrid(HW_ / 64, C_ / 64, B_);   // 625 x 4 x 2
        nchw_to_nhwc_h<<<tgrid, 256, 0, stream>>>(feat, nhwc, rois, perm);
        gather_nhwc<<<R_, 512, 0, stream>>>(nhwc, rois, perm, out);
    } else {
        const int n_out = R_ * C_ * NBINS;
        mono_kernel<<<(n_out + 255) / 256, 256, 0, stream>>>(feat, rois, out);
    }
}

// Round 2
// 174.564 us; speedup vs baseline: 1.0341x; 1.0214x over previous
//
#include <hip/hip_runtime.h>
#include <math.h>

// Problem constants (fixed by the reference file)
#define OUT_H 7
#define OUT_W 7
#define GS 2                      // SAMPLE_NUM
#define NBINS (OUT_H * OUT_W)     // 49
#define NSAMP (GS * GS)           // 4
#define SPATIAL_SCALE 0.25f
#define B_ 2
#define C_ 256
#define H_ 200
#define W_ 200
#define R_ 1000
#define HW_ (H_ * W_)             // 40000
#define NBMAX 13                  // max bins per quarter-block

typedef _Float16 half_t;
typedef __attribute__((ext_vector_type(8))) _Float16 half8;
typedef __attribute__((ext_vector_type(2))) _Float16 half2_t;
typedef __attribute__((ext_vector_type(4))) float f32x4;

// ============================================================================
// Fast path: XCD-banded roi order + fp16 NHWC transform + coalesced gather
// ============================================================================

// ---- NCHW fp32 -> NHWC fp16 tiled transpose (vectorized), with the
// roi->block permutation built by block (0,0,0).
// Swizzled LDS tile: float group g of row c stored at g ^ ((c^(c>>3))&7) ->
// conflict-free for both the b128 writes and the 8-consecutive-channel reads.
// tile: 64 channels x 64 hw. grid (625, 4, 2), block 256.
__global__ __launch_bounds__(256)
void nchw_to_nhwc_h(const float* __restrict__ in, half_t* __restrict__ out,
                    const float* __restrict__ rois, int* __restrict__ perm) {
    __shared__ float tile[64][64];       // 16 KB

    // ---- perm build (block 0 only; runs under the other blocks' traffic) ----
    __shared__ int cnt[8];
    __shared__ int novf, take;
    __shared__ unsigned char claimed[R_];
    __shared__ short ovf[R_];
    if (blockIdx.x == 0 && blockIdx.y == 0 && blockIdx.z == 0) {
        const int t0 = threadIdx.x;
        if (t0 < 8) cnt[t0] = 0;
        if (t0 == 0) { novf = 0; take = 0; }
        for (int t = t0; t < R_; t += 256) claimed[t] = 0;
        __syncthreads();
        for (int t = t0; t < R_; t += 256) {
            const float* roi = rois + t * 6;
            int   b   = (int)roi[0];
            float cyf = roi[2] * SPATIAL_SCALE;          // ~25..175
            int q = (int)((cyf - 25.0f) * (4.0f / 150.0f));
            q = q < 0 ? 0 : (q > 3 ? 3 : q);
            int band = b * 4 + q;
            band = band < 0 ? 0 : (band > 7 ? 7 : band);
            int rank = atomicAdd(&cnt[band], 1);
            if (rank < R_ / 8) {
                int id = band + 8 * rank;
                perm[id] = t;
                claimed[id] = 1;
            } else {
                ovf[atomicAdd(&novf, 1)] = (short)t;
            }
        }
        __syncthreads();
        for (int t = t0; t < R_; t += 256) {
            if (!claimed[t]) perm[t] = (int)ovf[atomicAdd(&take, 1)];
        }
    }

    const int hw0 = blockIdx.x * 64;     // 625 tiles
    const int c0  = blockIdx.y * 64;     // 4 chunks
    const int b   = blockIdx.z;
    const int t   = threadIdx.x;

    // read: f32x4 nontemporal (feat is read exactly once), 16 lanes per c-row
    {
        const f32x4* ip4 = (const f32x4*)(in + ((size_t)b * C_ + c0) * HW_ + hw0);
        const int r = t >> 4;            // 0..15
        const int q = t & 15;            // float4 index along hw
#pragma unroll
        for (int k = 0; k < 4; ++k) {
            const int c = r + 16 * k;
            f32x4 v = __builtin_nontemporal_load(&ip4[(size_t)c * (HW_ / 4) + q]);
            const int g = q ^ ((c ^ (c >> 3)) & 7);
            ((f32x4*)tile)[c * 16 + g] = v;
        }
    }
    __syncthreads();
    // write: thread = (hw row, 8-channel group); half8 16B stores
    {
        const int cg = t & 7;            // channel group (8 ch)
        const int hb = t >> 3;           // 0..31
        half_t* op = out + ((size_t)b * HW_ + hw0) * C_ + c0 + 8 * cg;
#pragma unroll
        for (int i = 0; i < 2; ++i) {
            const int hw = hb + 32 * i;
            const int gh = hw >> 2, oh = hw & 3;
            half8 h;
#pragma unroll
            for (int dc = 0; dc < 8; ++dc) {
                const int c = 8 * cg + dc;
                const float f = tile[c][4 * (gh ^ ((c ^ (c >> 3)) & 7)) + oh];
                h[dc] = (half_t)f;
            }
            *(half8*)(op + (size_t)hw * C_) = h;
        }
    }
}

// ---- mixed-precision FMA: acc += f16(half of pair) * w, fp32 accumulate ----
__device__ __forceinline__ void mix2(float& a0, float& a1,
                                     unsigned int pair, float w) {
    asm("v_fma_mix_f32 %0, %1, %2, %0 op_sel:[0,0,0] op_sel_hi:[1,0,0]"
        : "+v"(a0) : "v"(pair), "v"(w));
    asm("v_fma_mix_f32 %0, %1, %2, %0 op_sel:[1,0,0] op_sel_hi:[1,0,0]"
        : "+v"(a1) : "v"(pair), "v"(w));
}

// ---- body of one quarter-block: NB bins starting at B0 ----
// Inner loop: ALL 16 tap loads of a bin issued before any FMA (16-deep MLP),
// then 64 v_fma_mix (no separate f16->f32 cvts).
template<int NB>
__device__ __forceinline__ void gather_body(
        const uint2* __restrict__ fpu, int B0,
        const int4* __restrict__ s_o, const float4* __restrict__ s_w,
        int wave, int lane, int tid,
        float (&obuf)[4][64][NBMAX], float* __restrict__ out_r) {

    for (int j = wave; j < NB; j += 4) {
        const int m = j * NSAMP;
        const int4   o0 = s_o[m + 0], o1 = s_o[m + 1], o2 = s_o[m + 2], o3 = s_o[m + 3];
        const float4 w0 = s_w[m + 0], w1 = s_w[m + 1], w2 = s_w[m + 2], w3 = s_w[m + 3];

        // 16 tap loads (8B/lane, 512B/wave each) all in flight
        const uint2 t0  = fpu[o0.x + lane];
        const uint2 t1  = fpu[o0.y + lane];
        const uint2 t2  = fpu[o0.z + lane];
        const uint2 t3  = fpu[o0.w + lane];
        const uint2 t4  = fpu[o1.x + lane];
        const uint2 t5  = fpu[o1.y + lane];
        const uint2 t6  = fpu[o1.z + lane];
        const uint2 t7  = fpu[o1.w + lane];
        const uint2 t8  = fpu[o2.x + lane];
        const uint2 t9  = fpu[o2.y + lane];
        const uint2 t10 = fpu[o2.z + lane];
        const uint2 t11 = fpu[o2.w + lane];
        const uint2 t12 = fpu[o3.x + lane];
        const uint2 t13 = fpu[o3.y + lane];
        const uint2 t14 = fpu[o3.z + lane];
        const uint2 t15 = fpu[o3.w + lane];

        float ax = 0.0f, ay = 0.0f, az = 0.0f, aw = 0.0f;

        mix2(ax, ay, t0.x,  w0.x); mix2(az, aw, t0.y,  w0.x);
        mix2(ax, ay, t1.x,  w0.y); mix2(az, aw, t1.y,  w0.y);
        mix2(ax, ay, t2.x,  w0.z); mix2(az, aw, t2.y,  w0.z);
        mix2(ax, ay, t3.x,  w0.w); mix2(az, aw, t3.y,  w0.w);

        mix2(ax, ay, t4.x,  w1.x); mix2(az, aw, t4.y,  w1.x);
        mix2(ax, ay, t5.x,  w1.y); mix2(az, aw, t5.y,  w1.y);
        mix2(ax, ay, t6.x,  w1.z); mix2(az, aw, t6.y,  w1.z);
        mix2(ax, ay, t7.x,  w1.w); mix2(az, aw, t7.y,  w1.w);

        mix2(ax, ay, t8.x,  w2.x); mix2(az, aw, t8.y,  w2.x);
        mix2(ax, ay, t9.x,  w2.y); mix2(az, aw, t9.y,  w2.y);
        mix2(ax, ay, t10.x, w2.z); mix2(az, aw, t10.y, w2.z);
        mix2(ax, ay, t11.x, w2.w); mix2(az, aw, t11.y, w2.w);

        mix2(ax, ay, t12.x, w3.x); mix2(az, aw, t12.y, w3.x);
        mix2(ax, ay, t13.x, w3.y); mix2(az, aw, t13.y, w3.y);
        mix2(ax, ay, t14.x, w3.z); mix2(az, aw, t14.y, w3.z);
        mix2(ax, ay, t15.x, w3.w); mix2(az, aw, t15.y, w3.w);

        // staging: lane stride 13 floats (odd) -> conflict-free
        obuf[0][lane][j] = ax;   // c = 4*lane+0
        obuf[1][lane][j] = ay;   // c = 4*lane+1
        obuf[2][lane][j] = az;   // c = 4*lane+2
        obuf[3][lane][j] = aw;   // c = 4*lane+3
    }
    __syncthreads();

    // writeout: E = 256*NB is an exact multiple of 256
    const int E = C_ * NB;
    for (int e = tid; e < E; e += 256) {
        const int c = e / NB;
        const int j = e - c * NB;
        out_r[(size_t)c * NBINS + B0 + j] = obuf[c & 3][c >> 2][j];
    }
}

// ---- gather from fp16 NHWC: 4 quarter-blocks (256 thr) per roi, grid 4000.
// bid%1000 = perm slot keeps all 4 quarters of a roi on the SAME XCD
// (1000 % 8 == 0), preserving the spatial L2 banding and letting the
// quarters' partial output lines merge in that XCD's L2.
__global__ __launch_bounds__(256, 6)
void gather_nhwc(const half_t* __restrict__ nhwc,
                 const float* __restrict__ rois,
                 const int* __restrict__ perm,
                 float* __restrict__ out) {
    __shared__ float  obuf[4][64][NBMAX];   // 13312 B
    __shared__ int4   s_o[NBMAX * NSAMP];   // 832 B
    __shared__ float4 s_w[NBMAX * NSAMP];   // 832 B

    const int bid  = blockIdx.x;
    const int q    = bid / 1000;         // quarter 0..3
    const int slot = bid - q * 1000;
    const int r    = perm[slot];
    const int NB   = (q == 3) ? 13 : 12;
    const int B0   = 12 * q;

    const int tid  = threadIdx.x;
    const int wave = tid >> 6;   // 0..3
    const int lane = tid & 63;

    // ---- phase 0: per-(bin,sample) metadata (NB*4 <= 52 threads) ----
    if (tid < NB * NSAMP) {
        const float* roi = rois + r * 6;
        const int   b     = (int)roi[0];
        const float cx    = roi[1] * SPATIAL_SCALE - 0.5f;   // ALIGNED
        const float cy    = roi[2] * SPATIAL_SCALE - 0.5f;
        const float rw    = roi[3] * SPATIAL_SCALE;
        const float rh    = roi[4] * SPATIAL_SCALE;
        const float theta = roi[5];                           // CLOCKWISE == False
        const float bin_h = rh * (1.0f / OUT_H);
        const float bin_w = rw * (1.0f / OUT_W);
        float st, ct;
        __sincosf(theta, &st, &ct);

        const int bin = B0 + (tid >> 2);   // global bin
        const int s   = tid & 3;           // 0..3
        const int ph  = bin / OUT_W, pw = bin % OUT_W;
        const int iy  = s >> 1,      ix = s & 1;

        const float yy = -rh * 0.5f + ((float)ph + ((float)iy + 0.5f) * 0.5f) * bin_h;
        const float xx = -rw * 0.5f + ((float)pw + ((float)ix + 0.5f) * 0.5f) * bin_w;
        float x = yy * st + xx * ct + cx;
        float y = yy * ct - xx * st + cy;

        const bool valid = (y > -1.0f) && (y < (float)H_) &&
                           (x > -1.0f) && (x < (float)W_);
        y = fmaxf(y, 0.0f);
        x = fmaxf(x, 0.0f);
        int yl = (int)y, xl = (int)x;
        int yh; float ly;
        if (yl >= H_ - 1) { yl = H_ - 1; yh = H_ - 1; ly = 0.0f; }
        else              { yh = yl + 1; ly = y - (float)yl; }
        int xh; float lx;
        if (xl >= W_ - 1) { xl = W_ - 1; xh = W_ - 1; lx = 0.0f; }
        else              { xh = xl + 1; lx = x - (float)xl; }
        const float hy = 1.0f - ly, hx = 1.0f - lx;
        const float scale = valid ? (1.0f / NSAMP) : 0.0f;

        const int bplane = b * HW_;
        s_o[tid] = make_int4((bplane + yl * W_ + xl) * (C_ / 4),
                             (bplane + yl * W_ + xh) * (C_ / 4),
                             (bplane + yh * W_ + xl) * (C_ / 4),
                             (bplane + yh * W_ + xh) * (C_ / 4));
        s_w[tid] = make_float4(hy * hx * scale, hy * lx * scale,
                               ly * hx * scale, ly * lx * scale);
    }
    __syncthreads();

    const uint2* __restrict__ fpu = (const uint2*)nhwc;
    float* out_r = out + (size_t)r * (C_ * NBINS);

    if (q == 3) gather_body<13>(fpu, B0, s_o, s_w, wave, lane, tid, obuf, out_r);
    else        gather_body<12>(fpu, B0, s_o, s_w, wave, lane, tid, obuf, out_r);
}

// ============================================================================
// Fallback path (round-0 structure, known-passing)
// ============================================================================

struct alignas(16) Samp {
    int o0, o1, o2, o3;
    float w0, w1, w2, w3;
};

__device__ __forceinline__ Samp compute_samp(const float* __restrict__ rois,
                                             int r, int ph, int pw, int s) {
    const float* roi = rois + r * 6;
    int   b     = (int)roi[0];
    float cx    = roi[1] * SPATIAL_SCALE - 0.5f;
    float cy    = roi[2] * SPATIAL_SCALE - 0.5f;
    float rw    = roi[3] * SPATIAL_SCALE;
    float rh    = roi[4] * SPATIAL_SCALE;
    float theta = roi[5];
    float bin_h = rh * (1.0f / OUT_H);
    float bin_w = rw * (1.0f / OUT_W);
    int iy = s / GS, ix = s % GS;
    float yy = -rh * 0.5f + ((float)ph + ((float)iy + 0.5f) * (1.0f / GS)) * bin_h;
    float xx = -rw * 0.5f + ((float)pw + ((float)ix + 0.5f) * (1.0f / GS)) * bin_w;
    float st = sinf(theta), ct = cosf(theta);
    float x = yy * st + xx * ct + cx;
    float y = yy * ct - xx * st + cy;
    bool valid = (y > -1.0f) && (y < (float)H_) && (x > -1.0f) && (x < (float)W_);
    y = fmaxf(y, 0.0f);
    x = fmaxf(x, 0.0f);
    int yl = (int)y;
    int xl = (int)x;
    int yh; float ly;
    if (yl >= H_ - 1) { yl = H_ - 1; yh = H_ - 1; ly = 0.0f; }
    else              { yh = yl + 1; ly = y - (float)yl; }
    int xh; float lx;
    if (xl >= W_ - 1) { xl = W_ - 1; xh = W_ - 1; lx = 0.0f; }
    else              { xh = xl + 1; lx = x - (float)xl; }
    float hy = 1.0f - ly, hx = 1.0f - lx;
    float scale = valid ? (1.0f / NSAMP) : 0.0f;
    Samp sp;
    int base = b * (C_ * H_ * W_);
    sp.o0 = base + yl * W_ + xl;
    sp.o1 = base + yl * W_ + xh;
    sp.o2 = base + yh * W_ + xl;
    sp.o3 = base + yh * W_ + xh;
    sp.w0 = hy * hx * scale;
    sp.w1 = hy * lx * scale;
    sp.w2 = ly * hx * scale;
    sp.w3 = ly * lx * scale;
    return sp;
}

__global__ __launch_bounds__(256)
void mono_kernel(const float* __restrict__ feat,
                 const float* __restrict__ rois,
                 float* __restrict__ out) {
    int tid = blockIdx.x * blockDim.x + threadIdx.x;
    if (tid >= R_ * C_ * NBINS) return;
    int bin = tid % NBINS;
    int rc  = tid / NBINS;
    int c   = rc % C_;
    int r   = rc / C_;
    int coff = c * (H_ * W_);
    float acc = 0.0f;
#pragma unroll
    for (int s = 0; s < NSAMP; ++s) {
        Samp t = compute_samp(rois, r, bin / OUT_W, bin % OUT_W, s);
        acc += t.w0 * feat[coff + t.o0];
        acc += t.w1 * feat[coff + t.o1];
        acc += t.w2 * feat[coff + t.o2];
        acc += t.w3 * feat[coff + t.o3];
    }
    out[tid] = acc;
}

// ============================================================================

extern "C" void kernel_launch(void* const* d_in, const int* in_sizes, int n_in,
                              void* d_out, int out_size, void* d_ws, size_t ws_size,
                              hipStream_t stream) {
    const float* feat = (const float*)d_in[0];
    const float* rois = (const float*)d_in[1];
    float* out = (float*)d_out;

    const size_t nhwc_bytes = (size_t)B_ * C_ * HW_ * sizeof(half_t);  // 41 MB
    const size_t perm_bytes = (size_t)R_ * sizeof(int);

    if (ws_size >= nhwc_bytes + perm_bytes) {
        half_t* nhwc = (half_t*)d_ws;
        int*    perm = (int*)((char*)d_ws + nhwc_bytes);
        dim3 tgrid(HW_ / 64, C_ / 64, B_);   // 625 x 4 x 2
        nchw_to_nhwc_h<<<tgrid, 256, 0, stream>>>(feat, nhwc, rois, perm);
        gather_nhwc<<<4 * R_, 256, 0, stream>>>(nhwc, rois, perm, out);
    } else {
        const int n_out = R_ * C_ * NBINS;
        mono_kernel<<<(n_out + 255) / 256, 256, 0, stream>>>(feat, rois, out);
    }
}

// Round 3
// 158.716 us; speedup vs baseline: 1.1373x; 1.0998x over previous
//
#include <hip/hip_runtime.h>
#include <math.h>

// Problem constants (fixed by the reference file)
#define OUT_H 7
#define OUT_W 7
#define GS 2                      // SAMPLE_NUM
#define NBINS (OUT_H * OUT_W)     // 49
#define NSAMP (GS * GS)           // 4
#define NMETA (NBINS * NSAMP)     // 196
#define SPATIAL_SCALE 0.25f
#define B_ 2
#define C_ 256
#define H_ 200
#define W_ 200
#define R_ 1000
#define HW_ (H_ * W_)             // 40000

typedef _Float16 half_t;
typedef __attribute__((ext_vector_type(8))) _Float16 half8;
typedef __attribute__((ext_vector_type(2))) _Float16 half2_t;
typedef __attribute__((ext_vector_type(4))) float f32x4;

// ============================================================================
// Fast path: XCD-banded roi order + fp16 NHWC transform + coalesced gather
// ============================================================================

// ---- NCHW fp32 -> NHWC fp16 tiled transpose (vectorized), with the
// roi->block permutation built by block (0,0,0).
// Swizzled LDS tile: float group g of row c stored at g ^ ((c^(c>>3))&7) ->
// conflict-free for both the b128 writes and the 8-consecutive-channel reads.
// tile: 64 channels x 64 hw. grid (625, 4, 2), block 256.
__global__ __launch_bounds__(256)
void nchw_to_nhwc_h(const float* __restrict__ in, half_t* __restrict__ out,
                    const float* __restrict__ rois, int* __restrict__ perm) {
    __shared__ float tile[64][64];       // 16 KB

    // ---- perm build (block 0 only; runs under the other blocks' traffic) ----
    __shared__ int cnt[8];
    __shared__ int novf, take;
    __shared__ unsigned char claimed[R_];
    __shared__ short ovf[R_];
    if (blockIdx.x == 0 && blockIdx.y == 0 && blockIdx.z == 0) {
        const int t0 = threadIdx.x;
        if (t0 < 8) cnt[t0] = 0;
        if (t0 == 0) { novf = 0; take = 0; }
        for (int t = t0; t < R_; t += 256) claimed[t] = 0;
        __syncthreads();
        for (int t = t0; t < R_; t += 256) {
            const float* roi = rois + t * 6;
            int   b   = (int)roi[0];
            float cyf = roi[2] * SPATIAL_SCALE;          // ~25..175
            int q = (int)((cyf - 25.0f) * (4.0f / 150.0f));
            q = q < 0 ? 0 : (q > 3 ? 3 : q);
            int band = b * 4 + q;
            band = band < 0 ? 0 : (band > 7 ? 7 : band);
            int rank = atomicAdd(&cnt[band], 1);
            if (rank < R_ / 8) {
                int id = band + 8 * rank;
                perm[id] = t;
                claimed[id] = 1;
            } else {
                ovf[atomicAdd(&novf, 1)] = (short)t;
            }
        }
        __syncthreads();
        for (int t = t0; t < R_; t += 256) {
            if (!claimed[t]) perm[t] = (int)ovf[atomicAdd(&take, 1)];
        }
    }

    const int hw0 = blockIdx.x * 64;     // 625 tiles
    const int c0  = blockIdx.y * 64;     // 4 chunks
    const int b   = blockIdx.z;
    const int t   = threadIdx.x;

    // read: f32x4 nontemporal (feat is read exactly once), 16 lanes per c-row
    {
        const f32x4* ip4 = (const f32x4*)(in + ((size_t)b * C_ + c0) * HW_ + hw0);
        const int r = t >> 4;            // 0..15
        const int q = t & 15;            // float4 index along hw
#pragma unroll
        for (int k = 0; k < 4; ++k) {
            const int c = r + 16 * k;
            f32x4 v = __builtin_nontemporal_load(&ip4[(size_t)c * (HW_ / 4) + q]);
            const int g = q ^ ((c ^ (c >> 3)) & 7);
            ((f32x4*)tile)[c * 16 + g] = v;
        }
    }
    __syncthreads();
    // write: thread = (hw row, 8-channel group); half8 16B stores
    {
        const int cg = t & 7;            // channel group (8 ch)
        const int hb = t >> 3;           // 0..31
        half_t* op = out + ((size_t)b * HW_ + hw0) * C_ + c0 + 8 * cg;
#pragma unroll
        for (int i = 0; i < 2; ++i) {
            const int hw = hb + 32 * i;
            const int gh = hw >> 2, oh = hw & 3;
            half8 h;
#pragma unroll
            for (int dc = 0; dc < 8; ++dc) {
                const int c = 8 * cg + dc;
                const float f = tile[c][4 * (gh ^ ((c ^ (c >> 3)) & 7)) + oh];
                h[dc] = (half_t)f;
            }
            *(half8*)(op + (size_t)hw * C_) = h;
        }
    }
}

// ---- mixed-precision FMA: acc += f16(half of pair) * w, fp32 accumulate ----
__device__ __forceinline__ void mix2(float& a0, float& a1,
                                     unsigned int pair, float w) {
    asm("v_fma_mix_f32 %0, %1, %2, %0 op_sel:[0,0,0] op_sel_hi:[1,0,0]"
        : "+v"(a0) : "v"(pair), "v"(w));
    asm("v_fma_mix_f32 %0, %1, %2, %0 op_sel:[1,0,0] op_sel_hi:[1,0,0]"
        : "+v"(a1) : "v"(pair), "v"(w));
}

// ---- register block of one bin's 16 taps (8B/lane each) ----
struct Taps { uint2 t[16]; };

__device__ __forceinline__ void load_taps(Taps& T, const uint2* __restrict__ fpu,
                                          const int4* __restrict__ s_o,
                                          int m, int lane) {
#pragma unroll
    for (int i = 0; i < 4; ++i) {
        const int4 o = s_o[m + i];
        T.t[4 * i + 0] = fpu[o.x + lane];
        T.t[4 * i + 1] = fpu[o.y + lane];
        T.t[4 * i + 2] = fpu[o.z + lane];
        T.t[4 * i + 3] = fpu[o.w + lane];
    }
}

__device__ __forceinline__ void fma_store(const Taps& T,
                                          const float4* __restrict__ s_w,
                                          int m, int j, int lane,
                                          float (&obuf)[4][64][NBINS]) {
    float ax = 0.0f, ay = 0.0f, az = 0.0f, aw = 0.0f;
#pragma unroll
    for (int i = 0; i < 4; ++i) {
        const float4 w = s_w[m + i];
        mix2(ax, ay, T.t[4 * i + 0].x, w.x); mix2(az, aw, T.t[4 * i + 0].y, w.x);
        mix2(ax, ay, T.t[4 * i + 1].x, w.y); mix2(az, aw, T.t[4 * i + 1].y, w.y);
        mix2(ax, ay, T.t[4 * i + 2].x, w.z); mix2(az, aw, T.t[4 * i + 2].y, w.z);
        mix2(ax, ay, T.t[4 * i + 3].x, w.w); mix2(az, aw, T.t[4 * i + 3].y, w.w);
    }
    // dword index stride per lane = 49 (odd) -> 32 distinct banks, free
    obuf[0][lane][j] = ax;   // c = 4*lane+0
    obuf[1][lane][j] = ay;   // c = 4*lane+1
    obuf[2][lane][j] = az;   // c = 4*lane+2
    obuf[3][lane][j] = aw;   // c = 4*lane+3
}

// ---- gather from fp16 NHWC: one block (512 thr, 8 waves) per roi.
// Full-roi obuf (all 49 bins) -> ONE coalesced line-complete writeout
// (write-once nontemporal; no partial-line RMW, no cross-block merging).
// Ping-pong 2-bin pipeline: 32 tap loads in flight per wave (static reg
// names; launch_bounds(512,4) gives the 128-VGPR budget to hold them).
// LDS 56.4KB -> 2 blocks/CU.
__global__ __launch_bounds__(512, 4)
void gather_nhwc(const half_t* __restrict__ nhwc,
                 const float* __restrict__ rois,
                 const int* __restrict__ perm,
                 float* __restrict__ out) {
    __shared__ float  obuf[4][64][NBINS];   // 50176 B
    __shared__ int4   s_o[NMETA];           // 3136 B
    __shared__ float4 s_w[NMETA];           // 3136 B

    const int r    = perm[blockIdx.x];
    const int tid  = threadIdx.x;
    const int wave = tid >> 6;   // 0..7
    const int lane = tid & 63;

    // ---- phase 0: per-(bin,sample) metadata (196 of 512 threads) ----
    if (tid < NMETA) {
        const float* roi = rois + r * 6;
        const int   b     = (int)roi[0];
        const float cx    = roi[1] * SPATIAL_SCALE - 0.5f;   // ALIGNED
        const float cy    = roi[2] * SPATIAL_SCALE - 0.5f;
        const float rw    = roi[3] * SPATIAL_SCALE;
        const float rh    = roi[4] * SPATIAL_SCALE;
        const float theta = roi[5];                           // CLOCKWISE == False
        const float bin_h = rh * (1.0f / OUT_H);
        const float bin_w = rw * (1.0f / OUT_W);
        float st, ct;
        __sincosf(theta, &st, &ct);

        const int bin = tid >> 2;          // 0..48
        const int s   = tid & 3;           // 0..3
        const int ph  = bin / OUT_W, pw = bin % OUT_W;
        const int iy  = s >> 1,      ix = s & 1;

        const float yy = -rh * 0.5f + ((float)ph + ((float)iy + 0.5f) * 0.5f) * bin_h;
        const float xx = -rw * 0.5f + ((float)pw + ((float)ix + 0.5f) * 0.5f) * bin_w;
        float x = yy * st + xx * ct + cx;
        float y = yy * ct - xx * st + cy;

        const bool valid = (y > -1.0f) && (y < (float)H_) &&
                           (x > -1.0f) && (x < (float)W_);
        y = fmaxf(y, 0.0f);
        x = fmaxf(x, 0.0f);
        int yl = (int)y, xl = (int)x;
        int yh; float ly;
        if (yl >= H_ - 1) { yl = H_ - 1; yh = H_ - 1; ly = 0.0f; }
        else              { yh = yl + 1; ly = y - (float)yl; }
        int xh; float lx;
        if (xl >= W_ - 1) { xl = W_ - 1; xh = W_ - 1; lx = 0.0f; }
        else              { xh = xl + 1; lx = x - (float)xl; }
        const float hy = 1.0f - ly, hx = 1.0f - lx;
        const float scale = valid ? (1.0f / NSAMP) : 0.0f;

        const int bplane = b * HW_;
        s_o[tid] = make_int4((bplane + yl * W_ + xl) * (C_ / 4),
                             (bplane + yl * W_ + xh) * (C_ / 4),
                             (bplane + yh * W_ + xl) * (C_ / 4),
                             (bplane + yh * W_ + xh) * (C_ / 4));
        s_w[tid] = make_float4(hy * hx * scale, hy * lx * scale,
                               ly * hx * scale, ly * lx * scale);
    }
    __syncthreads();

    const uint2* __restrict__ fpu = (const uint2*)nhwc;

    // ---- ping-pong pipelined bin loop (bins wave, wave+8, ... < 49) ----
    {
        Taps A, B;
        int j = wave;
        load_taps(A, fpu, s_o, 4 * j, lane);
        while (true) {
            const int j2 = j + 8;
            if (j2 < NBINS) {
                load_taps(B, fpu, s_o, 4 * j2, lane);
                fma_store(A, s_w, 4 * j, j, lane, obuf);
                const int j3 = j2 + 8;
                if (j3 < NBINS) {
                    load_taps(A, fpu, s_o, 4 * j3, lane);
                    fma_store(B, s_w, 4 * j2, j2, lane, obuf);
                    j = j3;
                    continue;
                }
                fma_store(B, s_w, 4 * j2, j2, lane, obuf);
                break;
            }
            fma_store(A, s_w, 4 * j, j, lane, obuf);
            break;
        }
    }
    __syncthreads();

    // ---- single coalesced writeout: 12544 consecutive floats per roi ----
    // (write-once data: nontemporal, keep L2 for the tap band)
    float* out_r = out + (size_t)r * (C_ * NBINS);
    const int E = C_ * NBINS;            // 12544
#pragma unroll
    for (int i = 0; i < (E + 511) / 512; ++i) {
        const int f = tid + 512 * i;
        if (f < E) {
            const int c = f / NBINS;
            const int j = f - c * NBINS;
            __builtin_nontemporal_store(obuf[c & 3][c >> 2][j], &out_r[f]);
        }
    }
}

// ============================================================================
// Fallback path (round-0 structure, known-passing)
// ============================================================================

struct alignas(16) Samp {
    int o0, o1, o2, o3;
    float w0, w1, w2, w3;
};

__device__ __forceinline__ Samp compute_samp(const float* __restrict__ rois,
                                             int r, int ph, int pw, int s) {
    const float* roi = rois + r * 6;
    int   b     = (int)roi[0];
    float cx    = roi[1] * SPATIAL_SCALE - 0.5f;
    float cy    = roi[2] * SPATIAL_SCALE - 0.5f;
    float rw    = roi[3] * SPATIAL_SCALE;
    float rh    = roi[4] * SPATIAL_SCALE;
    float theta = roi[5];
    float bin_h = rh * (1.0f / OUT_H);
    float bin_w = rw * (1.0f / OUT_W);
    int iy = s / GS, ix = s % GS;
    float yy = -rh * 0.5f + ((float)ph + ((float)iy + 0.5f) * (1.0f / GS)) * bin_h;
    float xx = -rw * 0.5f + ((float)pw + ((float)ix + 0.5f) * (1.0f / GS)) * bin_w;
    float st = sinf(theta), ct = cosf(theta);
    float x = yy * st + xx * ct + cx;
    float y = yy * ct - xx * st + cy;
    bool valid = (y > -1.0f) && (y < (float)H_) && (x > -1.0f) && (x < (float)W_);
    y = fmaxf(y, 0.0f);
    x = fmaxf(x, 0.0f);
    int yl = (int)y;
    int xl = (int)x;
    int yh; float ly;
    if (yl >= H_ - 1) { yl = H_ - 1; yh = H_ - 1; ly = 0.0f; }
    else              { yh = yl + 1; ly = y - (float)yl; }
    int xh; float lx;
    if (xl >= W_ - 1) { xl = W_ - 1; xh = W_ - 1; lx = 0.0f; }
    else              { xh = xl + 1; lx = x - (float)xl; }
    float hy = 1.0f - ly, hx = 1.0f - lx;
    float scale = valid ? (1.0f / NSAMP) : 0.0f;
    Samp sp;
    int base = b * (C_ * H_ * W_);
    sp.o0 = base + yl * W_ + xl;
    sp.o1 = base + yl * W_ + xh;
    sp.o2 = base + yh * W_ + xl;
    sp.o3 = base + yh * W_ + xh;
    sp.w0 = hy * hx * scale;
    sp.w1 = hy * lx * scale;
    sp.w2 = ly * hx * scale;
    sp.w3 = ly * lx * scale;
    return sp;
}

__global__ __launch_bounds__(256)
void mono_kernel(const float* __restrict__ feat,
                 const float* __restrict__ rois,
                 float* __restrict__ out) {
    int tid = blockIdx.x * blockDim.x + threadIdx.x;
    if (tid >= R_ * C_ * NBINS) return;
    int bin = tid % NBINS;
    int rc  = tid / NBINS;
    int c   = rc % C_;
    int r   = rc / C_;
    int coff = c * (H_ * W_);
    float acc = 0.0f;
#pragma unroll
    for (int s = 0; s < NSAMP; ++s) {
        Samp t = compute_samp(rois, r, bin / OUT_W, bin % OUT_W, s);
        acc += t.w0 * feat[coff + t.o0];
        acc += t.w1 * feat[coff + t.o1];
        acc += t.w2 * feat[coff + t.o2];
        acc += t.w3 * feat[coff + t.o3];
    }
    out[tid] = acc;
}

// ============================================================================

extern "C" void kernel_launch(void* const* d_in, const int* in_sizes, int n_in,
                              void* d_out, int out_size, void* d_ws, size_t ws_size,
                              hipStream_t stream) {
    const float* feat = (const float*)d_in[0];
    const float* rois = (const float*)d_in[1];
    float* out = (float*)d_out;

    const size_t nhwc_bytes = (size_t)B_ * C_ * HW_ * sizeof(half_t);  // 41 MB
    const size_t perm_bytes = (size_t)R_ * sizeof(int);

    if (ws_size >= nhwc_bytes + perm_bytes) {
        half_t* nhwc = (half_t*)d_ws;
        int*    perm = (int*)((char*)d_ws + nhwc_bytes);
        dim3 tgrid(HW_ / 64, C_ / 64, B_);   // 625 x 4 x 2
        nchw_to_nhwc_h<<<tgrid, 256, 0, stream>>>(feat, nhwc, rois, perm);
        gather_nhwc<<<R_, 512, 0, stream>>>(nhwc, rois, perm, out);
    } else {
        const int n_out = R_ * C_ * NBINS;
        mono_kernel<<<(n_out + 255) / 256, 256, 0, stream>>>(feat, rois, out);
    }
}

// Round 4
// 157.373 us; speedup vs baseline: 1.1470x; 1.0085x over previous
//
#include <hip/hip_runtime.h>
#include <math.h>

// Problem constants (fixed by the reference file)
#define OUT_H 7
#define OUT_W 7
#define GS 2                      // SAMPLE_NUM
#define NBINS (OUT_H * OUT_W)     // 49
#define NSAMP (GS * GS)           // 4
#define NMETA (NBINS * NSAMP)     // 196
#define SPATIAL_SCALE 0.25f
#define B_ 2
#define C_ 256
#define H_ 200
#define W_ 200
#define R_ 1000
#define HW_ (H_ * W_)             // 40000

typedef _Float16 half_t;
typedef __attribute__((ext_vector_type(8))) _Float16 half8;
typedef __attribute__((ext_vector_type(2))) _Float16 half2_t;
typedef __attribute__((ext_vector_type(4))) float f32x4;

// ============================================================================
// Fast path: XCD-banded roi order + fp16 NHWC transform + coalesced gather
// ============================================================================

// ---- NCHW fp32 -> NHWC fp16 tiled transpose (vectorized), with the
// roi->block permutation built by block (0,0,0).
// Swizzled LDS tile: float group g of row c stored at g ^ ((c^(c>>3))&7) ->
// conflict-free for both the b128 writes and the 8-consecutive-channel reads.
// tile: 64 channels x 64 hw. grid (625, 4, 2), block 256.
__global__ __launch_bounds__(256)
void nchw_to_nhwc_h(const float* __restrict__ in, half_t* __restrict__ out,
                    const float* __restrict__ rois, int* __restrict__ perm) {
    __shared__ float tile[64][64];       // 16 KB

    // ---- perm build (block 0 only; runs under the other blocks' traffic) ----
    __shared__ int cnt[8];
    __shared__ int novf, take;
    __shared__ unsigned char claimed[R_];
    __shared__ short ovf[R_];
    if (blockIdx.x == 0 && blockIdx.y == 0 && blockIdx.z == 0) {
        const int t0 = threadIdx.x;
        if (t0 < 8) cnt[t0] = 0;
        if (t0 == 0) { novf = 0; take = 0; }
        for (int t = t0; t < R_; t += 256) claimed[t] = 0;
        __syncthreads();
        for (int t = t0; t < R_; t += 256) {
            const float* roi = rois + t * 6;
            int   b   = (int)roi[0];
            float cyf = roi[2] * SPATIAL_SCALE;          // ~25..175
            int q = (int)((cyf - 25.0f) * (4.0f / 150.0f));
            q = q < 0 ? 0 : (q > 3 ? 3 : q);
            int band = b * 4 + q;
            band = band < 0 ? 0 : (band > 7 ? 7 : band);
            int rank = atomicAdd(&cnt[band], 1);
            if (rank < R_ / 8) {
                int id = band + 8 * rank;
                perm[id] = t;
                claimed[id] = 1;
            } else {
                ovf[atomicAdd(&novf, 1)] = (short)t;
            }
        }
        __syncthreads();
        for (int t = t0; t < R_; t += 256) {
            if (!claimed[t]) perm[t] = (int)ovf[atomicAdd(&take, 1)];
        }
    }

    const int hw0 = blockIdx.x * 64;     // 625 tiles
    const int c0  = blockIdx.y * 64;     // 4 chunks
    const int b   = blockIdx.z;
    const int t   = threadIdx.x;

    // read: f32x4 nontemporal (feat is read exactly once), 16 lanes per c-row
    {
        const f32x4* ip4 = (const f32x4*)(in + ((size_t)b * C_ + c0) * HW_ + hw0);
        const int r = t >> 4;            // 0..15
        const int q = t & 15;            // float4 index along hw
#pragma unroll
        for (int k = 0; k < 4; ++k) {
            const int c = r + 16 * k;
            f32x4 v = __builtin_nontemporal_load(&ip4[(size_t)c * (HW_ / 4) + q]);
            const int g = q ^ ((c ^ (c >> 3)) & 7);
            ((f32x4*)tile)[c * 16 + g] = v;
        }
    }
    __syncthreads();
    // write: thread = (hw row, 8-channel group); half8 16B stores
    {
        const int cg = t & 7;            // channel group (8 ch)
        const int hb = t >> 3;           // 0..31
        half_t* op = out + ((size_t)b * HW_ + hw0) * C_ + c0 + 8 * cg;
#pragma unroll
        for (int i = 0; i < 2; ++i) {
            const int hw = hb + 32 * i;
            const int gh = hw >> 2, oh = hw & 3;
            half8 h;
#pragma unroll
            for (int dc = 0; dc < 8; ++dc) {
                const int c = 8 * cg + dc;
                const float f = tile[c][4 * (gh ^ ((c ^ (c >> 3)) & 7)) + oh];
                h[dc] = (half_t)f;
            }
            *(half8*)(op + (size_t)hw * C_) = h;
        }
    }
}

// ---- mixed-precision FMA: acc += f16(half of pair) * w, fp32 accumulate ----
__device__ __forceinline__ void mix2(float& a0, float& a1,
                                     unsigned int pair, float w) {
    asm("v_fma_mix_f32 %0, %1, %2, %0 op_sel:[0,0,0] op_sel_hi:[1,0,0]"
        : "+v"(a0) : "v"(pair), "v"(w));
    asm("v_fma_mix_f32 %0, %1, %2, %0 op_sel:[1,0,0] op_sel_hi:[1,0,0]"
        : "+v"(a1) : "v"(pair), "v"(w));
}

// ---- register block of one bin's 16 taps (8B/lane each) ----
struct Taps { uint2 t[16]; };

__device__ __forceinline__ void load_taps(Taps& T, const uint2* __restrict__ fpu,
                                          const int4* __restrict__ s_o,
                                          int m, int lane) {
#pragma unroll
    for (int i = 0; i < 4; ++i) {
        const int4 o = s_o[m + i];
        T.t[4 * i + 0] = fpu[o.x + lane];
        T.t[4 * i + 1] = fpu[o.y + lane];
        T.t[4 * i + 2] = fpu[o.z + lane];
        T.t[4 * i + 3] = fpu[o.w + lane];
    }
}

__device__ __forceinline__ void fma_store(const Taps& T,
                                          const float4* __restrict__ s_w,
                                          int m, int j, int lane,
                                          float (&obuf)[4][64][NBINS]) {
    float ax = 0.0f, ay = 0.0f, az = 0.0f, aw = 0.0f;
#pragma unroll
    for (int i = 0; i < 4; ++i) {
        const float4 w = s_w[m + i];
        mix2(ax, ay, T.t[4 * i + 0].x, w.x); mix2(az, aw, T.t[4 * i + 0].y, w.x);
        mix2(ax, ay, T.t[4 * i + 1].x, w.y); mix2(az, aw, T.t[4 * i + 1].y, w.y);
        mix2(ax, ay, T.t[4 * i + 2].x, w.z); mix2(az, aw, T.t[4 * i + 2].y, w.z);
        mix2(ax, ay, T.t[4 * i + 3].x, w.w); mix2(az, aw, T.t[4 * i + 3].y, w.w);
    }
    // dword index stride per lane = 49 (odd) -> 32 distinct banks, free
    obuf[0][lane][j] = ax;   // c = 4*lane+0
    obuf[1][lane][j] = ay;   // c = 4*lane+1
    obuf[2][lane][j] = az;   // c = 4*lane+2
    obuf[3][lane][j] = aw;   // c = 4*lane+3
}

// ---- gather from fp16 NHWC: one block (512 thr, 8 waves) per roi.
// Full-roi obuf (all 49 bins) -> ONE coalesced line-complete writeout
// (write-once nontemporal; no partial-line RMW, no cross-block merging).
// Ping-pong 2-bin pipeline PINNED with sched_barrier(0): round-3's version
// compiled to VGPR_Count=32 (compiler sank the loads to just-before-use,
// killing the MLP). The barriers force all 16 next-bin loads to be EMITTED
// before the current bin's FMAs, so the compiler must hold both tap sets
// (~64 VGPR) and waits become counted vmcnt(16) instead of vmcnt(0).
// LDS 56.4KB -> 2 blocks/CU; launch_bounds(512,4) -> 128-VGPR budget.
__global__ __launch_bounds__(512, 4)
void gather_nhwc(const half_t* __restrict__ nhwc,
                 const float* __restrict__ rois,
                 const int* __restrict__ perm,
                 float* __restrict__ out) {
    __shared__ float  obuf[4][64][NBINS];   // 50176 B
    __shared__ int4   s_o[NMETA];           // 3136 B
    __shared__ float4 s_w[NMETA];           // 3136 B

    const int r    = perm[blockIdx.x];
    const int tid  = threadIdx.x;
    const int wave = tid >> 6;   // 0..7
    const int lane = tid & 63;

    // ---- phase 0: per-(bin,sample) metadata (196 of 512 threads) ----
    if (tid < NMETA) {
        const float* roi = rois + r * 6;
        const int   b     = (int)roi[0];
        const float cx    = roi[1] * SPATIAL_SCALE - 0.5f;   // ALIGNED
        const float cy    = roi[2] * SPATIAL_SCALE - 0.5f;
        const float rw    = roi[3] * SPATIAL_SCALE;
        const float rh    = roi[4] * SPATIAL_SCALE;
        const float theta = roi[5];                           // CLOCKWISE == False
        const float bin_h = rh * (1.0f / OUT_H);
        const float bin_w = rw * (1.0f / OUT_W);
        float st, ct;
        __sincosf(theta, &st, &ct);

        const int bin = tid >> 2;          // 0..48
        const int s   = tid & 3;           // 0..3
        const int ph  = bin / OUT_W, pw = bin % OUT_W;
        const int iy  = s >> 1,      ix = s & 1;

        const float yy = -rh * 0.5f + ((float)ph + ((float)iy + 0.5f) * 0.5f) * bin_h;
        const float xx = -rw * 0.5f + ((float)pw + ((float)ix + 0.5f) * 0.5f) * bin_w;
        float x = yy * st + xx * ct + cx;
        float y = yy * ct - xx * st + cy;

        const bool valid = (y > -1.0f) && (y < (float)H_) &&
                           (x > -1.0f) && (x < (float)W_);
        y = fmaxf(y, 0.0f);
        x = fmaxf(x, 0.0f);
        int yl = (int)y, xl = (int)x;
        int yh; float ly;
        if (yl >= H_ - 1) { yl = H_ - 1; yh = H_ - 1; ly = 0.0f; }
        else              { yh = yl + 1; ly = y - (float)yl; }
        int xh; float lx;
        if (xl >= W_ - 1) { xl = W_ - 1; xh = W_ - 1; lx = 0.0f; }
        else              { xh = xl + 1; lx = x - (float)xl; }
        const float hy = 1.0f - ly, hx = 1.0f - lx;
        const float scale = valid ? (1.0f / NSAMP) : 0.0f;

        const int bplane = b * HW_;
        s_o[tid] = make_int4((bplane + yl * W_ + xl) * (C_ / 4),
                             (bplane + yl * W_ + xh) * (C_ / 4),
                             (bplane + yh * W_ + xl) * (C_ / 4),
                             (bplane + yh * W_ + xh) * (C_ / 4));
        s_w[tid] = make_float4(hy * hx * scale, hy * lx * scale,
                               ly * hx * scale, ly * lx * scale);
    }
    __syncthreads();

    const uint2* __restrict__ fpu = (const uint2*)nhwc;

    // ---- ping-pong pipelined bin loop, schedule pinned by sched_barrier ----
    // Wave w owns bins w, w+8, ..., <49 (6 or 7 bins). Buffer A serves
    // w, w+16, w+32, w+48; buffer B serves w+8, w+24, w+40. All branch
    // conditions are wave-uniform.
    {
        Taps A, B;
        int jA = wave;
        int jB = wave + 8;
        load_taps(A, fpu, s_o, 4 * jA, lane);
        if (jB < NBINS) load_taps(B, fpu, s_o, 4 * jB, lane);
        __builtin_amdgcn_sched_barrier(0);

        // stage 1
        fma_store(A, s_w, 4 * jA, jA, lane, obuf);
        jA += 16;
        if (jA < NBINS) load_taps(A, fpu, s_o, 4 * jA, lane);
        __builtin_amdgcn_sched_barrier(0);
        if (jB < NBINS) {
            fma_store(B, s_w, 4 * jB, jB, lane, obuf);
            jB += 16;
            if (jB < NBINS) load_taps(B, fpu, s_o, 4 * jB, lane);
            __builtin_amdgcn_sched_barrier(0);
        }
        // stage 2
        if (jA < NBINS) {
            fma_store(A, s_w, 4 * jA, jA, lane, obuf);
            jA += 16;
            if (jA < NBINS) load_taps(A, fpu, s_o, 4 * jA, lane);
            __builtin_amdgcn_sched_barrier(0);
        }
        if (jB < NBINS) {
            fma_store(B, s_w, 4 * jB, jB, lane, obuf);
            jB += 16;
            if (jB < NBINS) load_taps(B, fpu, s_o, 4 * jB, lane);
            __builtin_amdgcn_sched_barrier(0);
        }
        // stage 3
        if (jA < NBINS) {
            fma_store(A, s_w, 4 * jA, jA, lane, obuf);
            jA += 16;
            if (jA < NBINS) load_taps(A, fpu, s_o, 4 * jA, lane);
            __builtin_amdgcn_sched_barrier(0);
        }
        if (jB < NBINS) {
            fma_store(B, s_w, 4 * jB, jB, lane, obuf);
            jB += 16;            // max start 15 -> last use at 47; no reload
        }
        // stage 4 (wave 0 only: jA == 48)
        if (jA < NBINS) {
            fma_store(A, s_w, 4 * jA, jA, lane, obuf);
        }
    }
    __syncthreads();

    // ---- single coalesced writeout: 12544 consecutive floats per roi ----
    // (write-once data: nontemporal, keep L2 for the tap band)
    float* out_r = out + (size_t)r * (C_ * NBINS);
    const int E = C_ * NBINS;            // 12544
#pragma unroll
    for (int i = 0; i < (E + 511) / 512; ++i) {
        const int f = tid + 512 * i;
        if (f < E) {
            const int c = f / NBINS;
            const int j = f - c * NBINS;
            __builtin_nontemporal_store(obuf[c & 3][c >> 2][j], &out_r[f]);
        }
    }
}

// ============================================================================
// Fallback path (round-0 structure, known-passing)
// ============================================================================

struct alignas(16) Samp {
    int o0, o1, o2, o3;
    float w0, w1, w2, w3;
};

__device__ __forceinline__ Samp compute_samp(const float* __restrict__ rois,
                                             int r, int ph, int pw, int s) {
    const float* roi = rois + r * 6;
    int   b     = (int)roi[0];
    float cx    = roi[1] * SPATIAL_SCALE - 0.5f;
    float cy    = roi[2] * SPATIAL_SCALE - 0.5f;
    float rw    = roi[3] * SPATIAL_SCALE;
    float rh    = roi[4] * SPATIAL_SCALE;
    float theta = roi[5];
    float bin_h = rh * (1.0f / OUT_H);
    float bin_w = rw * (1.0f / OUT_W);
    int iy = s / GS, ix = s % GS;
    float yy = -rh * 0.5f + ((float)ph + ((float)iy + 0.5f) * (1.0f / GS)) * bin_h;
    float xx = -rw * 0.5f + ((float)pw + ((float)ix + 0.5f) * (1.0f / GS)) * bin_w;
    float st = sinf(theta), ct = cosf(theta);
    float x = yy * st + xx * ct + cx;
    float y = yy * ct - xx * st + cy;
    bool valid = (y > -1.0f) && (y < (float)H_) && (x > -1.0f) && (x < (float)W_);
    y = fmaxf(y, 0.0f);
    x = fmaxf(x, 0.0f);
    int yl = (int)y;
    int xl = (int)x;
    int yh; float ly;
    if (yl >= H_ - 1) { yl = H_ - 1; yh = H_ - 1; ly = 0.0f; }
    else              { yh = yl + 1; ly = y - (float)yl; }
    int xh; float lx;
    if (xl >= W_ - 1) { xl = W_ - 1; xh = W_ - 1; lx = 0.0f; }
    else              { xh = xl + 1; lx = x - (float)xl; }
    float hy = 1.0f - ly, hx = 1.0f - lx;
    float scale = valid ? (1.0f / NSAMP) : 0.0f;
    Samp sp;
    int base = b * (C_ * H_ * W_);
    sp.o0 = base + yl * W_ + xl;
    sp.o1 = base + yl * W_ + xh;
    sp.o2 = base + yh * W_ + xl;
    sp.o3 = base + yh * W_ + xh;
    sp.w0 = hy * hx * scale;
    sp.w1 = hy * lx * scale;
    sp.w2 = ly * hx * scale;
    sp.w3 = ly * lx * scale;
    return sp;
}

__global__ __launch_bounds__(256)
void mono_kernel(const float* __restrict__ feat,
                 const float* __restrict__ rois,
                 float* __restrict__ out) {
    int tid = blockIdx.x * blockDim.x + threadIdx.x;
    if (tid >= R_ * C_ * NBINS) return;
    int bin = tid % NBINS;
    int rc  = tid / NBINS;
    int c   = rc % C_;
    int r   = rc / C_;
    int coff = c * (H_ * W_);
    float acc = 0.0f;
#pragma unroll
    for (int s = 0; s < NSAMP; ++s) {
        Samp t = compute_samp(rois, r, bin / OUT_W, bin % OUT_W, s);
        acc += t.w0 * feat[coff + t.o0];
        acc += t.w1 * feat[coff + t.o1];
        acc += t.w2 * feat[coff + t.o2];
        acc += t.w3 * feat[coff + t.o3];
    }
    out[tid] = acc;
}

// ============================================================================

extern "C" void kernel_launch(void* const* d_in, const int* in_sizes, int n_in,
                              void* d_out, int out_size, void* d_ws, size_t ws_size,
                              hipStream_t stream) {
    const float* feat = (const float*)d_in[0];
    const float* rois = (const float*)d_in[1];
    float* out = (float*)d_out;

    const size_t nhwc_bytes = (size_t)B_ * C_ * HW_ * sizeof(half_t);  // 41 MB
    const size_t perm_bytes = (size_t)R_ * sizeof(int);

    if (ws_size >= nhwc_bytes + perm_bytes) {
        half_t* nhwc = (half_t*)d_ws;
        int*    perm = (int*)((char*)d_ws + nhwc_bytes);
        dim3 tgrid(HW_ / 64, C_ / 64, B_);   // 625 x 4 x 2
        nchw_to_nhwc_h<<<tgrid, 256, 0, stream>>>(feat, nhwc, rois, perm);
        gather_nhwc<<<R_, 512, 0, stream>>>(nhwc, rois, perm, out);
    } else {
        const int n_out = R_ * C_ * NBINS;
        mono_kernel<<<(n_out + 255) / 256, 256, 0, stream>>>(feat, rois, out);
    }
}